// Round 1
// baseline (1351.203 us; speedup 1.0000x reference)
//
#include <hip/hip_runtime.h>
#include <hip/hip_bf16.h>
#include <stdint.h>

#define H 128

__device__ __forceinline__ unsigned pack_bf16x2(float a, float b){
  unsigned ua = __float_as_uint(a);
  unsigned ub = __float_as_uint(b);
  unsigned ra = (ua + 0x7fffu + ((ua >> 16) & 1u)) >> 16;   // RNE round to bf16
  unsigned rb = (ub + 0x7fffu + ((ub >> 16) & 1u)) >> 16;
  return ra | (rb << 16);
}
__device__ __forceinline__ float bf_lo(unsigned u){ return __uint_as_float(u << 16); }
__device__ __forceinline__ float bf_hi(unsigned u){ return __uint_as_float(u & 0xffff0000u); }

// h0 = PQ @ W_in + b_in ; V = (1,0)
__global__ void init_kernel(const float* __restrict__ PQ, const float* __restrict__ Win,
                            const float* __restrict__ bin, float* __restrict__ h,
                            float* __restrict__ V, int N){
  int lane = threadIdx.x & 63;
  int wid  = (blockIdx.x * blockDim.x + threadIdx.x) >> 6;
  int nw   = (gridDim.x * blockDim.x) >> 6;
  int c0 = 2*lane, c1 = c0 + 1;
  float w00 = Win[c0], w01 = Win[c1], w10 = Win[H+c0], w11 = Win[H+c1];
  float b0 = bin[c0], b1 = bin[c1];
  for (int n = wid; n < N; n += nw){
    float p0 = PQ[2*n], p1 = PQ[2*n+1];
    float2 hv; hv.x = p0*w00 + p1*w10 + b0; hv.y = p0*w01 + p1*w11 + b1;
    *reinterpret_cast<float2*>(h + (size_t)n*H + c0) = hv;
    if (lane == 0){ V[2*n] = 1.0f; V[2*n+1] = 0.0f; }
  }
}

__global__ void hist_kernel(const int* __restrict__ recv, int* __restrict__ deg, int E){
  int i = blockIdx.x*blockDim.x + threadIdx.x;
  int st = gridDim.x*blockDim.x;
  for (; i < E; i += st) atomicAdd(deg + recv[i], 1);
}

// single-block exclusive scan of deg[N] -> rowptr[N+1], cursor[N]
__global__ void scan_kernel(const int* __restrict__ deg, int* __restrict__ rowptr,
                            int* __restrict__ cursor, int N, int E){
  __shared__ int sdata[1024];
  int t = threadIdx.x;
  int chunk = (N + 1023) >> 10;
  int lo = t*chunk, hi = min(N, lo + chunk);
  int sum = 0;
  for (int i = lo; i < hi; ++i) sum += deg[i];
  sdata[t] = sum; __syncthreads();
  for (int off = 1; off < 1024; off <<= 1){
    int v = (t >= off) ? sdata[t-off] : 0;
    __syncthreads();
    sdata[t] += v;
    __syncthreads();
  }
  int run = sdata[t] - sum;   // exclusive prefix
  for (int i = lo; i < hi; ++i){
    rowptr[i] = run; cursor[i] = run; run += deg[i];
  }
  if (t == 1023) rowptr[N] = E;
}

__global__ void fill_kernel(const int* __restrict__ recv, const int* __restrict__ send,
                            int* __restrict__ cursor, int* __restrict__ eid,
                            int* __restrict__ ssort, int E){
  int i = blockIdx.x*blockDim.x + threadIdx.x;
  int st = gridDim.x*blockDim.x;
  for (; i < E; i += st){
    int pos = atomicAdd(cursor + recv[i], 1);
    eid[pos] = i;
    ssort[pos] = send[i];
  }
}

// m_src[n] = concat(V[n], h[n]) @ W_node + b_msg   (stored bf16x2-packed)
// 4 waves/block: wave w owns k-slice [32w, 32w+32) of h; lane owns cols (2j,2j+1)
__global__ void node_msg_kernel(const float* __restrict__ V, const float* __restrict__ h,
                                const float* __restrict__ Wmsg_l, const float* __restrict__ bmsg_l,
                                unsigned* __restrict__ msrc, int N){
  __shared__ float part[4][64][2];
  int lane = threadIdx.x & 63;
  int w    = threadIdx.x >> 6;
  int c0 = 2*lane, c1 = c0 + 1;
  float Wh0[32], Wh1[32];
  const float* Wh = Wmsg_l + 2*H;           // rows 2..129 multiply h
  #pragma unroll
  for (int i = 0; i < 32; ++i){
    int k = w*32 + i;
    Wh0[i] = Wh[(size_t)k*H + c0];
    Wh1[i] = Wh[(size_t)k*H + c1];
  }
  float Wv00=0, Wv01=0, Wv10=0, Wv11=0, bm0=0, bm1=0;
  if (w == 0){
    Wv00 = Wmsg_l[c0];     Wv01 = Wmsg_l[c1];
    Wv10 = Wmsg_l[H + c0]; Wv11 = Wmsg_l[H + c1];
    bm0  = bmsg_l[c0];     bm1  = bmsg_l[c1];
  }
  for (int n = blockIdx.x; n < N; n += gridDim.x){
    const float* hn = h + (size_t)n*H + w*32;
    float p0 = 0.f, p1 = 0.f;
    #pragma unroll
    for (int i = 0; i < 32; ++i){
      float x = hn[i];
      p0 += x*Wh0[i]; p1 += x*Wh1[i];
    }
    if (w == 0){
      float v0 = V[2*n], v1 = V[2*n+1];
      p0 += v0*Wv00 + v1*Wv10 + bm0;
      p1 += v0*Wv01 + v1*Wv11 + bm1;
    }
    part[w][lane][0] = p0; part[w][lane][1] = p1;
    __syncthreads();
    if (w == 0){
      float s0 = part[0][lane][0] + part[1][lane][0] + part[2][lane][0] + part[3][lane][0];
      float s1 = part[0][lane][1] + part[1][lane][1] + part[2][lane][1] + part[3][lane][1];
      msrc[(size_t)n*64 + lane] = pack_bf16x2(s0, s1);
    }
    __syncthreads();
  }
}

// per receiver node: acc = sum_e (m_src[s_e] + ef[e]@W_edge); h=relu(acc);
// dV = h@W_out + b_out; V += dV.  One wave per node, 2 cols per lane.
__global__ void agg_update_kernel(const unsigned* __restrict__ msrc,
                                  const int* __restrict__ rowptr,
                                  const int* __restrict__ eid,
                                  const int* __restrict__ ssort,
                                  const float* __restrict__ ef,
                                  const float* __restrict__ Wmsg_l,
                                  const float* __restrict__ Wout_l,
                                  const float* __restrict__ bout_l,
                                  const float* __restrict__ Vin,
                                  float* __restrict__ Vout,
                                  float* __restrict__ h, int N){
  int lane = threadIdx.x & 63;
  int wid  = (blockIdx.x*blockDim.x + threadIdx.x) >> 6;
  int nw   = (gridDim.x*blockDim.x) >> 6;
  int c0 = 2*lane, c1 = c0 + 1;
  float We00 = Wmsg_l[(size_t)130*H + c0], We01 = Wmsg_l[(size_t)130*H + c1];
  float We10 = Wmsg_l[(size_t)131*H + c0], We11 = Wmsg_l[(size_t)131*H + c1];
  float We20 = Wmsg_l[(size_t)132*H + c0], We21 = Wmsg_l[(size_t)132*H + c1];
  float We30 = Wmsg_l[(size_t)133*H + c0], We31 = Wmsg_l[(size_t)133*H + c1];
  float Wo00 = Wout_l[c0*2], Wo01 = Wout_l[c0*2+1];
  float Wo10 = Wout_l[c1*2], Wo11 = Wout_l[c1*2+1];
  float bo0 = bout_l[0], bo1 = bout_l[1];
  for (int n = wid; n < N; n += nw){
    int beg = rowptr[n], end = rowptr[n+1];
    float acc0 = 0.f, acc1 = 0.f;
    for (int i = beg; i < end; ++i){
      int e = eid[i];
      int s = ssort[i];
      float4 f = *reinterpret_cast<const float4*>(ef + (size_t)e*4);
      unsigned u = msrc[(size_t)s*64 + lane];
      acc0 += bf_lo(u) + f.x*We00 + f.y*We10 + f.z*We20 + f.w*We30;
      acc1 += bf_hi(u) + f.x*We01 + f.y*We11 + f.z*We21 + f.w*We31;
    }
    float a0 = fmaxf(acc0, 0.f), a1 = fmaxf(acc1, 0.f);
    *reinterpret_cast<float2*>(h + (size_t)n*H + c0) = make_float2(a0, a1);
    float p0 = a0*Wo00 + a1*Wo10;
    float p1 = a0*Wo01 + a1*Wo11;
    #pragma unroll
    for (int off = 32; off > 0; off >>= 1){
      p0 += __shfl_xor(p0, off, 64);
      p1 += __shfl_xor(p1, off, 64);
    }
    if (lane == 0){
      float v0 = Vin[2*n], v1 = Vin[2*n+1];
      Vout[2*n]   = v0 + p0 + bo0;
      Vout[2*n+1] = v1 + p1 + bo1;
    }
  }
}

extern "C" void kernel_launch(void* const* d_in, const int* in_sizes, int n_in,
                              void* d_out, int out_size, void* d_ws, size_t ws_size,
                              hipStream_t stream){
  const float* PQ      = (const float*)d_in[0];
  const int*   senders = (const int*)  d_in[1];
  const int*   recv    = (const int*)  d_in[2];
  const float* ef      = (const float*)d_in[3];
  const float* Win     = (const float*)d_in[4];
  const float* bin     = (const float*)d_in[5];
  const float* Wmsg    = (const float*)d_in[6];
  const float* bmsg    = (const float*)d_in[7];
  const float* Wout    = (const float*)d_in[8];
  const float* bout    = (const float*)d_in[9];
  int N = in_sizes[0] / 2;
  int E = in_sizes[1];
  int L = in_sizes[7] / H;          // 3 layers
  int MSG_IN = in_sizes[6] / (L * H);  // 134 (unused directly; rows fixed below)
  (void)MSG_IN;

  char* base = (char*)d_ws;
  size_t off = 0;
  auto alloc = [&](size_t bytes)->char*{
    char* p = base + off; off += (bytes + 255) & ~(size_t)255; return p;
  };
  float*    h      = (float*)   alloc((size_t)N*H*4);
  unsigned* msrc   = (unsigned*)alloc((size_t)N*64*4);
  float*    V      = (float*)   alloc((size_t)N*2*4);
  int*      deg    = (int*)     alloc((size_t)N*4);
  int*      rowptr = (int*)     alloc((size_t)(N+1)*4);
  int*      cursor = (int*)     alloc((size_t)N*4);
  int*      eid    = (int*)     alloc((size_t)E*4);
  int*      ssort  = (int*)     alloc((size_t)E*4);
  if (off > ws_size) return;   // workspace too small -> fail loudly via wrong output

  hipMemsetAsync(deg, 0, (size_t)N*4, stream);
  init_kernel<<<2048, 256, 0, stream>>>(PQ, Win, bin, h, V, N);
  hist_kernel<<<1024, 256, 0, stream>>>(recv, deg, E);
  scan_kernel<<<1, 1024, 0, stream>>>(deg, rowptr, cursor, N, E);
  fill_kernel<<<1024, 256, 0, stream>>>(recv, senders, cursor, eid, ssort, E);

  for (int l = 0; l < L; ++l){
    const float* Wmsg_l = Wmsg + (size_t)l*134*H;
    const float* bmsg_l = bmsg + (size_t)l*H;
    const float* Wout_l = Wout + (size_t)l*H*2;
    const float* bout_l = bout + (size_t)l*2;
    node_msg_kernel<<<4096, 256, 0, stream>>>(V, h, Wmsg_l, bmsg_l, msrc, N);
    float* Vout = (l == L-1) ? (float*)d_out : V;
    agg_update_kernel<<<2048, 256, 0, stream>>>(msrc, rowptr, eid, ssort, ef,
                                                Wmsg_l, Wout_l, bout_l, V, Vout, h, N);
  }
}

// Round 5
// 1090.961 us; speedup vs baseline: 1.2385x; 1.2385x over previous
//
#include <hip/hip_runtime.h>
#include <hip/hip_bf16.h>
#include <stdint.h>

#define H 128
#define SCAN_B 1024

__device__ __forceinline__ unsigned pack_bf16x2(float a, float b){
  unsigned ua = __float_as_uint(a);
  unsigned ub = __float_as_uint(b);
  unsigned ra = (ua + 0x7fffu + ((ua >> 16) & 1u)) >> 16;   // RNE round to bf16
  unsigned rb = (ub + 0x7fffu + ((ub >> 16) & 1u)) >> 16;
  return ra | (rb << 16);
}
__device__ __forceinline__ float bf_lo(unsigned u){ return __uint_as_float(u << 16); }
__device__ __forceinline__ float bf_hi(unsigned u){ return __uint_as_float(u & 0xffff0000u); }

// h0 = PQ @ W_in + b_in ; V = (1,0)
__global__ void init_kernel(const float* __restrict__ PQ, const float* __restrict__ Win,
                            const float* __restrict__ bin, float* __restrict__ h,
                            float* __restrict__ V, int N){
  int lane = threadIdx.x & 63;
  int wid  = (blockIdx.x * blockDim.x + threadIdx.x) >> 6;
  int nw   = (gridDim.x * blockDim.x) >> 6;
  int c0 = 2*lane, c1 = c0 + 1;
  float w00 = Win[c0], w01 = Win[c1], w10 = Win[H+c0], w11 = Win[H+c1];
  float b0 = bin[c0], b1 = bin[c1];
  for (int n = wid; n < N; n += nw){
    float p0 = PQ[2*n], p1 = PQ[2*n+1];
    float2 hv; hv.x = p0*w00 + p1*w10 + b0; hv.y = p0*w01 + p1*w11 + b1;
    *reinterpret_cast<float2*>(h + (size_t)n*H + c0) = hv;
    if (lane == 0){ V[2*n] = 1.0f; V[2*n+1] = 0.0f; }
  }
}

__global__ void hist_kernel(const int* __restrict__ recv, int* __restrict__ deg, int E){
  int i = blockIdx.x*blockDim.x + threadIdx.x;
  int st = gridDim.x*blockDim.x;
  for (; i < E; i += st) atomicAdd(deg + recv[i], 1);
}

// ---- 3-phase device-wide exclusive scan of deg[N] ----
__global__ void scan1_kernel(const int* __restrict__ deg, int* __restrict__ rowptr,
                             int* __restrict__ bsum, int N){
  __shared__ int s[SCAN_B];
  int t = threadIdx.x;
  int i = blockIdx.x*SCAN_B + t;
  int v = (i < N) ? deg[i] : 0;
  s[t] = v; __syncthreads();
  #pragma unroll
  for (int off = 1; off < SCAN_B; off <<= 1){
    int x = (t >= off) ? s[t-off] : 0;
    __syncthreads();
    s[t] += x;
    __syncthreads();
  }
  int incl = s[t];
  if (i < N) rowptr[i] = incl - v;            // block-local exclusive
  if (t == SCAN_B-1) bsum[blockIdx.x] = incl; // block total
}

__global__ void scan2_kernel(int* __restrict__ bsum, int* __restrict__ bexcl, int nb){
  __shared__ int s[SCAN_B];
  int t = threadIdx.x;
  int v = (t < nb) ? bsum[t] : 0;
  s[t] = v; __syncthreads();
  #pragma unroll
  for (int off = 1; off < SCAN_B; off <<= 1){
    int x = (t >= off) ? s[t-off] : 0;
    __syncthreads();
    s[t] += x;
    __syncthreads();
  }
  if (t < nb) bexcl[t] = s[t] - v;
}

__global__ void scan3_kernel(int* __restrict__ rowptr, int* __restrict__ cursor,
                             const int* __restrict__ bexcl, int N, int E){
  int i = blockIdx.x*SCAN_B + threadIdx.x;
  if (i < N){
    int r = rowptr[i] + bexcl[blockIdx.x];
    rowptr[i] = r;
    cursor[i] = r;
  }
  if (i == 0) rowptr[N] = E;
}

__global__ void fill_kernel(const int* __restrict__ recv, const int* __restrict__ send,
                            int* __restrict__ cursor, int* __restrict__ eid,
                            int* __restrict__ ssort, int E){
  int i = blockIdx.x*blockDim.x + threadIdx.x;
  int st = gridDim.x*blockDim.x;
  for (; i < E; i += st){
    int pos = atomicAdd(cursor + recv[i], 1);
    eid[pos] = i;
    ssort[pos] = send[i];
  }
}

// m_src[n] = concat(V[n], h[n]) @ W_node + b_msg   (stored bf16x2-packed)
// 4 waves/block: wave w owns k-slice [32w, 32w+32) of h; lane owns cols (2j,2j+1)
__global__ void node_msg_kernel(const float* __restrict__ V, const float* __restrict__ h,
                                const float* __restrict__ Wmsg_l, const float* __restrict__ bmsg_l,
                                unsigned* __restrict__ msrc, int N){
  __shared__ float part[4][64][2];
  int lane = threadIdx.x & 63;
  int w    = threadIdx.x >> 6;
  int c0 = 2*lane, c1 = c0 + 1;
  float Wh0[32], Wh1[32];
  const float* Wh = Wmsg_l + 2*H;           // rows 2..129 multiply h
  #pragma unroll
  for (int i = 0; i < 32; ++i){
    int k = w*32 + i;
    Wh0[i] = Wh[(size_t)k*H + c0];
    Wh1[i] = Wh[(size_t)k*H + c1];
  }
  float Wv00=0, Wv01=0, Wv10=0, Wv11=0, bm0=0, bm1=0;
  if (w == 0){
    Wv00 = Wmsg_l[c0];     Wv01 = Wmsg_l[c1];
    Wv10 = Wmsg_l[H + c0]; Wv11 = Wmsg_l[H + c1];
    bm0  = bmsg_l[c0];     bm1  = bmsg_l[c1];
  }
  for (int n = blockIdx.x; n < N; n += gridDim.x){
    const float* hn = h + (size_t)n*H + w*32;
    float p0 = 0.f, p1 = 0.f;
    #pragma unroll
    for (int i = 0; i < 32; ++i){
      float x = hn[i];
      p0 += x*Wh0[i]; p1 += x*Wh1[i];
    }
    if (w == 0){
      float v0 = V[2*n], v1 = V[2*n+1];
      p0 += v0*Wv00 + v1*Wv10 + bm0;
      p1 += v0*Wv01 + v1*Wv11 + bm1;
    }
    part[w][lane][0] = p0; part[w][lane][1] = p1;
    __syncthreads();
    if (w == 0){
      float s0 = part[0][lane][0] + part[1][lane][0] + part[2][lane][0] + part[3][lane][0];
      float s1 = part[0][lane][1] + part[1][lane][1] + part[2][lane][1] + part[3][lane][1];
      msrc[(size_t)n*64 + lane] = pack_bf16x2(s0, s1);
    }
    __syncthreads();
  }
}

// per receiver node: acc = sum_e m_src[s_e]  (+ edge-feature term);
// h = relu(acc); dV = h@W_out + b_out; V += dV.  One wave per node.
// FIRST layer: gathers ef per edge and also writes efsum[n] = sum_e ef[e].
// Later layers: edge-feature term = efsum[n] @ We (hoisted out of the loop).
template<bool FIRST>
__global__ void agg_update_kernel(const unsigned* __restrict__ msrc,
                                  const int* __restrict__ rowptr,
                                  const int* __restrict__ eid,
                                  const int* __restrict__ ssort,
                                  const float* __restrict__ ef,
                                  const float* __restrict__ Wmsg_l,
                                  const float* __restrict__ Wout_l,
                                  const float* __restrict__ bout_l,
                                  const float* __restrict__ Vin,
                                  float* __restrict__ Vout,
                                  float* __restrict__ h,
                                  float4* __restrict__ efsum, int N){
  int lane = threadIdx.x & 63;
  int wid  = (blockIdx.x*blockDim.x + threadIdx.x) >> 6;
  int nw   = (gridDim.x*blockDim.x) >> 6;
  int c0 = 2*lane, c1 = c0 + 1;
  float We00 = Wmsg_l[(size_t)130*H + c0], We01 = Wmsg_l[(size_t)130*H + c1];
  float We10 = Wmsg_l[(size_t)131*H + c0], We11 = Wmsg_l[(size_t)131*H + c1];
  float We20 = Wmsg_l[(size_t)132*H + c0], We21 = Wmsg_l[(size_t)132*H + c1];
  float We30 = Wmsg_l[(size_t)133*H + c0], We31 = Wmsg_l[(size_t)133*H + c1];
  float Wo00 = Wout_l[c0*2], Wo01 = Wout_l[c0*2+1];
  float Wo10 = Wout_l[c1*2], Wo11 = Wout_l[c1*2+1];
  float bo0 = bout_l[0], bo1 = bout_l[1];
  for (int n = wid; n < N; n += nw){
    int beg = rowptr[n], end = rowptr[n+1];
    float acc0 = 0.f, acc1 = 0.f;
    float sfx = 0.f, sfy = 0.f, sfz = 0.f, sfw = 0.f;
    if (FIRST){
      for (int i = beg; i < end; ++i){
        int e = eid[i];
        int s = ssort[i];
        float4 f = *reinterpret_cast<const float4*>(ef + (size_t)e*4);
        unsigned u = msrc[(size_t)s*64 + lane];
        acc0 += bf_lo(u); acc1 += bf_hi(u);
        sfx += f.x; sfy += f.y; sfz += f.z; sfw += f.w;
      }
      if (lane == 0) efsum[n] = make_float4(sfx, sfy, sfz, sfw);
    } else {
      for (int i = beg; i < end; ++i){
        int s = ssort[i];
        unsigned u = msrc[(size_t)s*64 + lane];
        acc0 += bf_lo(u); acc1 += bf_hi(u);
      }
      float4 f = efsum[n];
      sfx = f.x; sfy = f.y; sfz = f.z; sfw = f.w;
    }
    acc0 += sfx*We00 + sfy*We10 + sfz*We20 + sfw*We30;
    acc1 += sfx*We01 + sfy*We11 + sfz*We21 + sfw*We31;
    float a0 = fmaxf(acc0, 0.f), a1 = fmaxf(acc1, 0.f);
    *reinterpret_cast<float2*>(h + (size_t)n*H + c0) = make_float2(a0, a1);
    float p0 = a0*Wo00 + a1*Wo10;
    float p1 = a0*Wo01 + a1*Wo11;
    #pragma unroll
    for (int off = 32; off > 0; off >>= 1){
      p0 += __shfl_xor(p0, off, 64);
      p1 += __shfl_xor(p1, off, 64);
    }
    if (lane == 0){
      float v0 = Vin[2*n], v1 = Vin[2*n+1];
      Vout[2*n]   = v0 + p0 + bo0;
      Vout[2*n+1] = v1 + p1 + bo1;
    }
  }
}

extern "C" void kernel_launch(void* const* d_in, const int* in_sizes, int n_in,
                              void* d_out, int out_size, void* d_ws, size_t ws_size,
                              hipStream_t stream){
  const float* PQ      = (const float*)d_in[0];
  const int*   senders = (const int*)  d_in[1];
  const int*   recv    = (const int*)  d_in[2];
  const float* ef      = (const float*)d_in[3];
  const float* Win     = (const float*)d_in[4];
  const float* bin     = (const float*)d_in[5];
  const float* Wmsg    = (const float*)d_in[6];
  const float* bmsg    = (const float*)d_in[7];
  const float* Wout    = (const float*)d_in[8];
  const float* bout    = (const float*)d_in[9];
  int N = in_sizes[0] / 2;
  int E = in_sizes[1];
  int L = in_sizes[7] / H;          // 3 layers

  char* base = (char*)d_ws;
  size_t off = 0;
  auto alloc = [&](size_t bytes)->char*{
    char* p = base + off; off += (bytes + 255) & ~(size_t)255; return p;
  };
  float*    h      = (float*)   alloc((size_t)N*H*4);
  unsigned* msrc   = (unsigned*)alloc((size_t)N*64*4);
  float*    V      = (float*)   alloc((size_t)N*2*4);
  int*      deg    = (int*)     alloc((size_t)N*4);
  int*      rowptr = (int*)     alloc((size_t)(N+1)*4);
  int*      cursor = (int*)     alloc((size_t)N*4);
  int*      eid    = (int*)     alloc((size_t)E*4);
  int*      ssort  = (int*)     alloc((size_t)E*4);
  float4*   efsum  = (float4*)  alloc((size_t)N*16);
  int*      bsum   = (int*)     alloc((size_t)SCAN_B*4);
  int*      bexcl  = (int*)     alloc((size_t)SCAN_B*4);
  if (off > ws_size) return;

  int nb = (N + SCAN_B - 1) / SCAN_B;   // 98 blocks

  hipMemsetAsync(deg, 0, (size_t)N*4, stream);
  init_kernel<<<2048, 256, 0, stream>>>(PQ, Win, bin, h, V, N);
  hist_kernel<<<1024, 256, 0, stream>>>(recv, deg, E);
  scan1_kernel<<<nb, SCAN_B, 0, stream>>>(deg, rowptr, bsum, N);
  scan2_kernel<<<1, SCAN_B, 0, stream>>>(bsum, bexcl, nb);
  scan3_kernel<<<nb, SCAN_B, 0, stream>>>(rowptr, cursor, bexcl, N, E);
  fill_kernel<<<1024, 256, 0, stream>>>(recv, senders, cursor, eid, ssort, E);

  for (int l = 0; l < L; ++l){
    const float* Wmsg_l = Wmsg + (size_t)l*134*H;
    const float* bmsg_l = bmsg + (size_t)l*H;
    const float* Wout_l = Wout + (size_t)l*H*2;
    const float* bout_l = bout + (size_t)l*2;
    node_msg_kernel<<<4096, 256, 0, stream>>>(V, h, Wmsg_l, bmsg_l, msrc, N);
    float* Vout = (l == L-1) ? (float*)d_out : V;
    if (l == 0)
      agg_update_kernel<true><<<2048, 256, 0, stream>>>(msrc, rowptr, eid, ssort, ef,
                                                        Wmsg_l, Wout_l, bout_l, V, Vout, h, efsum, N);
    else
      agg_update_kernel<false><<<2048, 256, 0, stream>>>(msrc, rowptr, eid, ssort, ef,
                                                         Wmsg_l, Wout_l, bout_l, V, Vout, h, efsum, N);
  }
}

// Round 6
// 977.651 us; speedup vs baseline: 1.3821x; 1.1159x over previous
//
#include <hip/hip_runtime.h>
#include <hip/hip_bf16.h>
#include <stdint.h>

#define H 128
#define SCAN_B 1024

__device__ __forceinline__ unsigned pack_bf16x2(float a, float b){
  unsigned ua = __float_as_uint(a);
  unsigned ub = __float_as_uint(b);
  unsigned ra = (ua + 0x7fffu + ((ua >> 16) & 1u)) >> 16;   // RNE round to bf16
  unsigned rb = (ub + 0x7fffu + ((ub >> 16) & 1u)) >> 16;
  return ra | (rb << 16);
}
__device__ __forceinline__ float bf_lo(unsigned u){ return __uint_as_float(u << 16); }
__device__ __forceinline__ float bf_hi(unsigned u){ return __uint_as_float(u & 0xffff0000u); }

// h0 = pack_bf16(PQ @ W_in + b_in) ; V = (1,0).  h stored as bf16x2 (64 uints/node).
__global__ void init_kernel(const float* __restrict__ PQ, const float* __restrict__ Win,
                            const float* __restrict__ bin, unsigned* __restrict__ h,
                            float* __restrict__ V, int N){
  int lane = threadIdx.x & 63;
  int wid  = (blockIdx.x * blockDim.x + threadIdx.x) >> 6;
  int nw   = (gridDim.x * blockDim.x) >> 6;
  int c0 = 2*lane, c1 = c0 + 1;
  float w00 = Win[c0], w01 = Win[c1], w10 = Win[H+c0], w11 = Win[H+c1];
  float b0 = bin[c0], b1 = bin[c1];
  for (int n = wid; n < N; n += nw){
    float p0 = PQ[2*n], p1 = PQ[2*n+1];
    float h0 = p0*w00 + p1*w10 + b0;
    float h1 = p0*w01 + p1*w11 + b1;
    h[(size_t)n*64 + lane] = pack_bf16x2(h0, h1);
    if (lane == 0){ V[2*n] = 1.0f; V[2*n+1] = 0.0f; }
  }
}

__global__ void hist_kernel(const int* __restrict__ recv, int* __restrict__ deg, int E){
  int i = blockIdx.x*blockDim.x + threadIdx.x;
  int st = gridDim.x*blockDim.x;
  for (; i < E; i += st) atomicAdd(deg + recv[i], 1);
}

// ---- 3-phase device-wide exclusive scan of deg[N] ----
__global__ void scan1_kernel(const int* __restrict__ deg, int* __restrict__ rowptr,
                             int* __restrict__ bsum, int N){
  __shared__ int s[SCAN_B];
  int t = threadIdx.x;
  int i = blockIdx.x*SCAN_B + t;
  int v = (i < N) ? deg[i] : 0;
  s[t] = v; __syncthreads();
  #pragma unroll
  for (int off = 1; off < SCAN_B; off <<= 1){
    int x = (t >= off) ? s[t-off] : 0;
    __syncthreads();
    s[t] += x;
    __syncthreads();
  }
  int incl = s[t];
  if (i < N) rowptr[i] = incl - v;            // block-local exclusive
  if (t == SCAN_B-1) bsum[blockIdx.x] = incl; // block total
}

__global__ void scan2_kernel(int* __restrict__ bsum, int* __restrict__ bexcl, int nb){
  __shared__ int s[SCAN_B];
  int t = threadIdx.x;
  int v = (t < nb) ? bsum[t] : 0;
  s[t] = v; __syncthreads();
  #pragma unroll
  for (int off = 1; off < SCAN_B; off <<= 1){
    int x = (t >= off) ? s[t-off] : 0;
    __syncthreads();
    s[t] += x;
    __syncthreads();
  }
  if (t < nb) bexcl[t] = s[t] - v;
}

__global__ void scan3_kernel(int* __restrict__ rowptr, int* __restrict__ cursor,
                             const int* __restrict__ bexcl, int N, int E){
  int i = blockIdx.x*SCAN_B + threadIdx.x;
  if (i < N){
    int r = rowptr[i] + bexcl[blockIdx.x];
    rowptr[i] = r;
    cursor[i] = r;
  }
  if (i == 0) rowptr[N] = E;
}

__global__ void fill_kernel(const int* __restrict__ recv, const int* __restrict__ send,
                            int* __restrict__ cursor, int* __restrict__ eid,
                            int* __restrict__ ssort, int E){
  int i = blockIdx.x*blockDim.x + threadIdx.x;
  int st = gridDim.x*blockDim.x;
  for (; i < E; i += st){
    int pos = atomicAdd(cursor + recv[i], 1);
    eid[pos] = i;
    ssort[pos] = send[i];
  }
}

// m_src[n] = concat(V[n], h[n]) @ W_node + b_msg   (stored bf16x2-packed)
// 4 waves/block: wave w owns k-slice [32w, 32w+32) of h; lane owns cols (2j,2j+1)
// h is bf16x2-packed: node row = 64 uints; wave w reads uints [16w, 16w+16).
__global__ void node_msg_kernel(const float* __restrict__ V, const unsigned* __restrict__ h,
                                const float* __restrict__ Wmsg_l, const float* __restrict__ bmsg_l,
                                unsigned* __restrict__ msrc, int N){
  __shared__ float part[4][64][2];
  int lane = threadIdx.x & 63;
  int w    = threadIdx.x >> 6;
  int c0 = 2*lane, c1 = c0 + 1;
  float Wh0[32], Wh1[32];
  const float* Wh = Wmsg_l + 2*H;           // rows 2..129 multiply h
  #pragma unroll
  for (int i = 0; i < 32; ++i){
    int k = w*32 + i;
    Wh0[i] = Wh[(size_t)k*H + c0];
    Wh1[i] = Wh[(size_t)k*H + c1];
  }
  float Wv00=0, Wv01=0, Wv10=0, Wv11=0, bm0=0, bm1=0;
  if (w == 0){
    Wv00 = Wmsg_l[c0];     Wv01 = Wmsg_l[c1];
    Wv10 = Wmsg_l[H + c0]; Wv11 = Wmsg_l[H + c1];
    bm0  = bmsg_l[c0];     bm1  = bmsg_l[c1];
  }
  for (int n = blockIdx.x; n < N; n += gridDim.x){
    const unsigned* hn = h + (size_t)n*64 + w*16;
    float p0 = 0.f, p1 = 0.f;
    #pragma unroll
    for (int i = 0; i < 16; ++i){
      unsigned u = hn[i];
      float x0 = bf_lo(u), x1 = bf_hi(u);
      p0 += x0*Wh0[2*i] + x1*Wh0[2*i+1];
      p1 += x0*Wh1[2*i] + x1*Wh1[2*i+1];
    }
    if (w == 0){
      float v0 = V[2*n], v1 = V[2*n+1];
      p0 += v0*Wv00 + v1*Wv10 + bm0;
      p1 += v0*Wv01 + v1*Wv11 + bm1;
    }
    part[w][lane][0] = p0; part[w][lane][1] = p1;
    __syncthreads();
    if (w == 0){
      float s0 = part[0][lane][0] + part[1][lane][0] + part[2][lane][0] + part[3][lane][0];
      float s1 = part[0][lane][1] + part[1][lane][1] + part[2][lane][1] + part[3][lane][1];
      msrc[(size_t)n*64 + lane] = pack_bf16x2(s0, s1);
    }
    __syncthreads();
  }
}

// per receiver node: acc = sum_e m_src[s_e]  (+ edge-feature term);
// h = relu(acc) (bf16-packed); dV = h@W_out + b_out; V += dV.  One wave per node.
// Edge loop: 64-edge chunks; lane l holds ssort[c+l]; __shfl broadcast; msrc
// gathers unrolled x4 (4 VMEM in flight -> latency hiding).
// FIRST: lane accumulates its own edges' ef; butterfly-reduce once per node.
template<bool FIRST>
__global__ void agg_update_kernel(const unsigned* __restrict__ msrc,
                                  const int* __restrict__ rowptr,
                                  const int* __restrict__ eid,
                                  const int* __restrict__ ssort,
                                  const float* __restrict__ ef,
                                  const float* __restrict__ Wmsg_l,
                                  const float* __restrict__ Wout_l,
                                  const float* __restrict__ bout_l,
                                  const float* __restrict__ Vin,
                                  float* __restrict__ Vout,
                                  unsigned* __restrict__ h,
                                  float4* __restrict__ efsum, int N){
  int lane = threadIdx.x & 63;
  int wid  = (blockIdx.x*blockDim.x + threadIdx.x) >> 6;
  int nw   = (gridDim.x*blockDim.x) >> 6;
  int c0 = 2*lane, c1 = c0 + 1;
  float We00 = Wmsg_l[(size_t)130*H + c0], We01 = Wmsg_l[(size_t)130*H + c1];
  float We10 = Wmsg_l[(size_t)131*H + c0], We11 = Wmsg_l[(size_t)131*H + c1];
  float We20 = Wmsg_l[(size_t)132*H + c0], We21 = Wmsg_l[(size_t)132*H + c1];
  float We30 = Wmsg_l[(size_t)133*H + c0], We31 = Wmsg_l[(size_t)133*H + c1];
  float Wo00 = Wout_l[c0*2], Wo01 = Wout_l[c0*2+1];
  float Wo10 = Wout_l[c1*2], Wo11 = Wout_l[c1*2+1];
  float bo0 = bout_l[0], bo1 = bout_l[1];
  for (int n = wid; n < N; n += nw){
    int beg = rowptr[n], end = rowptr[n+1];
    float acc0 = 0.f, acc1 = 0.f;
    float sfx = 0.f, sfy = 0.f, sfz = 0.f, sfw = 0.f;
    for (int c = beg; c < end; c += 64){
      int inlane = (c + lane < end);
      int sv = inlane ? ssort[c + lane] : 0;
      if (FIRST && inlane){
        int e = eid[c + lane];
        float4 f = *reinterpret_cast<const float4*>(ef + (size_t)e*4);
        sfx += f.x; sfy += f.y; sfz += f.z; sfw += f.w;
      }
      int kmax = min(64, end - c);
      int j = 0;
      for (; j + 4 <= kmax; j += 4){
        int s0 = __shfl(sv, j,   64);
        int s1 = __shfl(sv, j+1, 64);
        int s2 = __shfl(sv, j+2, 64);
        int s3 = __shfl(sv, j+3, 64);
        unsigned u0 = msrc[(size_t)s0*64 + lane];
        unsigned u1 = msrc[(size_t)s1*64 + lane];
        unsigned u2 = msrc[(size_t)s2*64 + lane];
        unsigned u3 = msrc[(size_t)s3*64 + lane];
        acc0 += bf_lo(u0) + bf_lo(u1) + bf_lo(u2) + bf_lo(u3);
        acc1 += bf_hi(u0) + bf_hi(u1) + bf_hi(u2) + bf_hi(u3);
      }
      for (; j < kmax; ++j){
        int s = __shfl(sv, j, 64);
        unsigned u = msrc[(size_t)s*64 + lane];
        acc0 += bf_lo(u); acc1 += bf_hi(u);
      }
    }
    if (FIRST){
      #pragma unroll
      for (int off = 32; off > 0; off >>= 1){
        sfx += __shfl_xor(sfx, off, 64);
        sfy += __shfl_xor(sfy, off, 64);
        sfz += __shfl_xor(sfz, off, 64);
        sfw += __shfl_xor(sfw, off, 64);
      }
      if (lane == 0) efsum[n] = make_float4(sfx, sfy, sfz, sfw);
    } else {
      float4 f = efsum[n];
      sfx = f.x; sfy = f.y; sfz = f.z; sfw = f.w;
    }
    acc0 += sfx*We00 + sfy*We10 + sfz*We20 + sfw*We30;
    acc1 += sfx*We01 + sfy*We11 + sfz*We21 + sfw*We31;
    float a0 = fmaxf(acc0, 0.f), a1 = fmaxf(acc1, 0.f);
    h[(size_t)n*64 + lane] = pack_bf16x2(a0, a1);
    float p0 = a0*Wo00 + a1*Wo10;
    float p1 = a0*Wo01 + a1*Wo11;
    #pragma unroll
    for (int off = 32; off > 0; off >>= 1){
      p0 += __shfl_xor(p0, off, 64);
      p1 += __shfl_xor(p1, off, 64);
    }
    if (lane == 0){
      float v0 = Vin[2*n], v1 = Vin[2*n+1];
      Vout[2*n]   = v0 + p0 + bo0;
      Vout[2*n+1] = v1 + p1 + bo1;
    }
  }
}

extern "C" void kernel_launch(void* const* d_in, const int* in_sizes, int n_in,
                              void* d_out, int out_size, void* d_ws, size_t ws_size,
                              hipStream_t stream){
  const float* PQ      = (const float*)d_in[0];
  const int*   senders = (const int*)  d_in[1];
  const int*   recv    = (const int*)  d_in[2];
  const float* ef      = (const float*)d_in[3];
  const float* Win     = (const float*)d_in[4];
  const float* bin     = (const float*)d_in[5];
  const float* Wmsg    = (const float*)d_in[6];
  const float* bmsg    = (const float*)d_in[7];
  const float* Wout    = (const float*)d_in[8];
  const float* bout    = (const float*)d_in[9];
  int N = in_sizes[0] / 2;
  int E = in_sizes[1];
  int L = in_sizes[7] / H;          // 3 layers

  char* base = (char*)d_ws;
  size_t off = 0;
  auto alloc = [&](size_t bytes)->char*{
    char* p = base + off; off += (bytes + 255) & ~(size_t)255; return p;
  };
  unsigned* h      = (unsigned*)alloc((size_t)N*64*4);   // bf16x2-packed
  unsigned* msrc   = (unsigned*)alloc((size_t)N*64*4);
  float*    V      = (float*)   alloc((size_t)N*2*4);
  int*      deg    = (int*)     alloc((size_t)N*4);
  int*      rowptr = (int*)     alloc((size_t)(N+1)*4);
  int*      cursor = (int*)     alloc((size_t)N*4);
  int*      eid    = (int*)     alloc((size_t)E*4);
  int*      ssort  = (int*)     alloc((size_t)E*4);
  float4*   efsum  = (float4*)  alloc((size_t)N*16);
  int*      bsum   = (int*)     alloc((size_t)SCAN_B*4);
  int*      bexcl  = (int*)     alloc((size_t)SCAN_B*4);
  if (off > ws_size) return;

  int nb = (N + SCAN_B - 1) / SCAN_B;   // 98 blocks

  hipMemsetAsync(deg, 0, (size_t)N*4, stream);
  init_kernel<<<2048, 256, 0, stream>>>(PQ, Win, bin, h, V, N);
  hist_kernel<<<1024, 256, 0, stream>>>(recv, deg, E);
  scan1_kernel<<<nb, SCAN_B, 0, stream>>>(deg, rowptr, bsum, N);
  scan2_kernel<<<1, SCAN_B, 0, stream>>>(bsum, bexcl, nb);
  scan3_kernel<<<nb, SCAN_B, 0, stream>>>(rowptr, cursor, bexcl, N, E);
  fill_kernel<<<1024, 256, 0, stream>>>(recv, senders, cursor, eid, ssort, E);

  for (int l = 0; l < L; ++l){
    const float* Wmsg_l = Wmsg + (size_t)l*134*H;
    const float* bmsg_l = bmsg + (size_t)l*H;
    const float* Wout_l = Wout + (size_t)l*H*2;
    const float* bout_l = bout + (size_t)l*2;
    node_msg_kernel<<<4096, 256, 0, stream>>>(V, h, Wmsg_l, bmsg_l, msrc, N);
    float* Vout = (l == L-1) ? (float*)d_out : V;
    if (l == 0)
      agg_update_kernel<true><<<2048, 256, 0, stream>>>(msrc, rowptr, eid, ssort, ef,
                                                        Wmsg_l, Wout_l, bout_l, V, Vout, h, efsum, N);
    else
      agg_update_kernel<false><<<2048, 256, 0, stream>>>(msrc, rowptr, eid, ssort, ef,
                                                         Wmsg_l, Wout_l, bout_l, V, Vout, h, efsum, N);
  }
}

// Round 7
// 601.956 us; speedup vs baseline: 2.2447x; 1.6241x over previous
//
#include <hip/hip_runtime.h>
#include <hip/hip_bf16.h>
#include <stdint.h>

#define H 128
#define SCAN_B 1024

typedef __attribute__((ext_vector_type(8))) short bf16x8;
typedef __attribute__((ext_vector_type(4))) float f32x4;

__device__ __forceinline__ unsigned pack_bf16x2(float a, float b){
  unsigned ua = __float_as_uint(a);
  unsigned ub = __float_as_uint(b);
  unsigned ra = (ua + 0x7fffu + ((ua >> 16) & 1u)) >> 16;   // RNE round to bf16
  unsigned rb = (ub + 0x7fffu + ((ub >> 16) & 1u)) >> 16;
  return ra | (rb << 16);
}
__device__ __forceinline__ float bf_lo(unsigned u){ return __uint_as_float(u << 16); }
__device__ __forceinline__ float bf_hi(unsigned u){ return __uint_as_float(u & 0xffff0000u); }

// h0 = pack_bf16(PQ @ W_in + b_in) ; V = (1,0).  h stored as bf16x2 (64 uints/node).
__global__ void init_kernel(const float* __restrict__ PQ, const float* __restrict__ Win,
                            const float* __restrict__ bin, unsigned* __restrict__ h,
                            float* __restrict__ V, int N){
  int lane = threadIdx.x & 63;
  int wid  = (blockIdx.x * blockDim.x + threadIdx.x) >> 6;
  int nw   = (gridDim.x * blockDim.x) >> 6;
  int c0 = 2*lane, c1 = c0 + 1;
  float w00 = Win[c0], w01 = Win[c1], w10 = Win[H+c0], w11 = Win[H+c1];
  float b0 = bin[c0], b1 = bin[c1];
  for (int n = wid; n < N; n += nw){
    float p0 = PQ[2*n], p1 = PQ[2*n+1];
    float h0 = p0*w00 + p1*w10 + b0;
    float h1 = p0*w01 + p1*w11 + b1;
    h[(size_t)n*64 + lane] = pack_bf16x2(h0, h1);
    if (lane == 0){ V[2*n] = 1.0f; V[2*n+1] = 0.0f; }
  }
}

__global__ void hist_kernel(const int* __restrict__ recv, int* __restrict__ deg, int E){
  int i = blockIdx.x*blockDim.x + threadIdx.x;
  int st = gridDim.x*blockDim.x;
  for (; i < E; i += st) atomicAdd(deg + recv[i], 1);
}

// ---- 3-phase device-wide exclusive scan of deg[N] ----
__global__ void scan1_kernel(const int* __restrict__ deg, int* __restrict__ rowptr,
                             int* __restrict__ bsum, int N){
  __shared__ int s[SCAN_B];
  int t = threadIdx.x;
  int i = blockIdx.x*SCAN_B + t;
  int v = (i < N) ? deg[i] : 0;
  s[t] = v; __syncthreads();
  #pragma unroll
  for (int off = 1; off < SCAN_B; off <<= 1){
    int x = (t >= off) ? s[t-off] : 0;
    __syncthreads();
    s[t] += x;
    __syncthreads();
  }
  int incl = s[t];
  if (i < N) rowptr[i] = incl - v;            // block-local exclusive
  if (t == SCAN_B-1) bsum[blockIdx.x] = incl; // block total
}

__global__ void scan2_kernel(int* __restrict__ bsum, int* __restrict__ bexcl, int nb){
  __shared__ int s[SCAN_B];
  int t = threadIdx.x;
  int v = (t < nb) ? bsum[t] : 0;
  s[t] = v; __syncthreads();
  #pragma unroll
  for (int off = 1; off < SCAN_B; off <<= 1){
    int x = (t >= off) ? s[t-off] : 0;
    __syncthreads();
    s[t] += x;
    __syncthreads();
  }
  if (t < nb) bexcl[t] = s[t] - v;
}

__global__ void scan3_kernel(int* __restrict__ rowptr, int* __restrict__ cursor,
                             const int* __restrict__ bexcl, int N, int E){
  int i = blockIdx.x*SCAN_B + threadIdx.x;
  if (i < N){
    int r = rowptr[i] + bexcl[blockIdx.x];
    rowptr[i] = r;
    cursor[i] = r;
  }
  if (i == 0) rowptr[N] = E;
}

__global__ void fill_kernel(const int* __restrict__ recv, const int* __restrict__ send,
                            int* __restrict__ cursor, int* __restrict__ eid,
                            int* __restrict__ ssort, int E){
  int i = blockIdx.x*blockDim.x + threadIdx.x;
  int st = gridDim.x*blockDim.x;
  for (; i < E; i += st){
    int pos = atomicAdd(cursor + recv[i], 1);
    eid[pos] = i;
    ssort[pos] = send[i];
  }
}

// Pre-pack Wh (rows 2..129 of Wmsg, [128][128]) into per-lane MFMA B-fragment
// order, bf16x2.  Fragment f = ct*4+ks; lane holds B[k=ks*32+(lane>>4)*8+j][col=ct*16+(lane&15)].
// Wb layout: uint4[layer][2048 frag-lanes] -> frag*64+lane.
__global__ void wprep_kernel(const float* __restrict__ Wmsg, unsigned* __restrict__ Wb, int L){
  int t = blockIdx.x*blockDim.x + threadIdx.x;
  if (t >= L*2048) return;
  int layer = t >> 11;
  int f = t & 2047;
  int ct   = f >> 8;
  int ks   = (f >> 6) & 3;
  int lane = f & 63;
  int col = ct*16 + (lane & 15);
  int kbase = ks*32 + (lane >> 4)*8;
  const float* Wl = Wmsg + (size_t)layer*134*H + 2*H;   // Wh rows
  unsigned u0 = pack_bf16x2(Wl[(size_t)(kbase+0)*H + col], Wl[(size_t)(kbase+1)*H + col]);
  unsigned u1 = pack_bf16x2(Wl[(size_t)(kbase+2)*H + col], Wl[(size_t)(kbase+3)*H + col]);
  unsigned u2 = pack_bf16x2(Wl[(size_t)(kbase+4)*H + col], Wl[(size_t)(kbase+5)*H + col]);
  unsigned u3 = pack_bf16x2(Wl[(size_t)(kbase+6)*H + col], Wl[(size_t)(kbase+7)*H + col]);
  uint4* dst = reinterpret_cast<uint4*>(Wb) + (size_t)layer*2048 + f;
  *dst = make_uint4(u0, u1, u2, u3);
}

// msrc = pack_bf16( h @ Wh  +  V @ Wv + b )  via MFMA.
// One wave = 16 nodes x 128 cols: 8 col-tiles(ct) x 4 K-steps(ks) of
// mfma_f32_16x16x32_bf16.  A: row=lane&15, k=(lane>>4)*8+j (h's packed layout
// IS this order).  C/D: col=lane&15, row=(lane>>4)*4+reg  [m89-verified].
__global__ void node_msg_mfma(const float* __restrict__ V, const unsigned* __restrict__ h,
                              const float* __restrict__ Wmsg_l, const float* __restrict__ bmsg_l,
                              const unsigned* __restrict__ Wb_l, unsigned* __restrict__ msrc, int N){
  int lane = threadIdx.x & 63;
  int gw   = (blockIdx.x*blockDim.x + threadIdx.x) >> 6;
  int nwv  = (gridDim.x*blockDim.x) >> 6;
  int row = lane & 15, kg = lane >> 4;
  int ntiles = N >> 4;                      // N divisible by 16 (100000/16=6250)
  const bf16x8* wb = reinterpret_cast<const bf16x8*>(Wb_l);
  for (int t = gw; t < ntiles; t += nwv){
    int node0 = t << 4;
    const bf16x8* hrow = reinterpret_cast<const bf16x8*>(h + (size_t)(node0 + row)*64);
    bf16x8 a[4];
    #pragma unroll
    for (int ks = 0; ks < 4; ++ks) a[ks] = hrow[ks*4 + kg];
    float2 vv[4];
    #pragma unroll
    for (int r = 0; r < 4; ++r)
      vv[r] = *reinterpret_cast<const float2*>(V + 2*(node0 + kg*4 + r));
    #pragma unroll
    for (int ct = 0; ct < 8; ++ct){
      f32x4 acc = {0.f, 0.f, 0.f, 0.f};
      #pragma unroll
      for (int ks = 0; ks < 4; ++ks){
        bf16x8 b = wb[(ct*4 + ks)*64 + lane];
        acc = __builtin_amdgcn_mfma_f32_16x16x32_bf16(a[ks], b, acc, 0, 0, 0);
      }
      int col = ct*16 + row;
      float wv0 = Wmsg_l[col], wv1 = Wmsg_l[H + col], bb = bmsg_l[col];
      #pragma unroll
      for (int r = 0; r < 4; ++r){
        float o = acc[r] + vv[r].x*wv0 + vv[r].y*wv1 + bb;
        float oh = __shfl_xor(o, 1, 64);
        if (!(lane & 1)){
          int nr = node0 + kg*4 + r;
          msrc[(size_t)nr*64 + ct*8 + (row >> 1)] = pack_bf16x2(o, oh);
        }
      }
    }
  }
}

// per receiver node: acc = sum_e m_src[s_e]  (+ edge-feature term);
// h = relu(acc) (bf16-packed); dV = h@W_out + b_out; V += dV.  One wave per node.
template<bool FIRST>
__global__ void agg_update_kernel(const unsigned* __restrict__ msrc,
                                  const int* __restrict__ rowptr,
                                  const int* __restrict__ eid,
                                  const int* __restrict__ ssort,
                                  const float* __restrict__ ef,
                                  const float* __restrict__ Wmsg_l,
                                  const float* __restrict__ Wout_l,
                                  const float* __restrict__ bout_l,
                                  const float* __restrict__ Vin,
                                  float* __restrict__ Vout,
                                  unsigned* __restrict__ h,
                                  float4* __restrict__ efsum, int N){
  int lane = threadIdx.x & 63;
  int wid  = (blockIdx.x*blockDim.x + threadIdx.x) >> 6;
  int nw   = (gridDim.x*blockDim.x) >> 6;
  int c0 = 2*lane, c1 = c0 + 1;
  float We00 = Wmsg_l[(size_t)130*H + c0], We01 = Wmsg_l[(size_t)130*H + c1];
  float We10 = Wmsg_l[(size_t)131*H + c0], We11 = Wmsg_l[(size_t)131*H + c1];
  float We20 = Wmsg_l[(size_t)132*H + c0], We21 = Wmsg_l[(size_t)132*H + c1];
  float We30 = Wmsg_l[(size_t)133*H + c0], We31 = Wmsg_l[(size_t)133*H + c1];
  float Wo00 = Wout_l[c0*2], Wo01 = Wout_l[c0*2+1];
  float Wo10 = Wout_l[c1*2], Wo11 = Wout_l[c1*2+1];
  float bo0 = bout_l[0], bo1 = bout_l[1];
  for (int n = wid; n < N; n += nw){
    int beg = rowptr[n], end = rowptr[n+1];
    float acc0 = 0.f, acc1 = 0.f;
    float sfx = 0.f, sfy = 0.f, sfz = 0.f, sfw = 0.f;
    for (int c = beg; c < end; c += 64){
      int inlane = (c + lane < end);
      int sv = inlane ? ssort[c + lane] : 0;
      if (FIRST && inlane){
        int e = eid[c + lane];
        float4 f = *reinterpret_cast<const float4*>(ef + (size_t)e*4);
        sfx += f.x; sfy += f.y; sfz += f.z; sfw += f.w;
      }
      int kmax = min(64, end - c);
      int j = 0;
      for (; j + 4 <= kmax; j += 4){
        int s0 = __shfl(sv, j,   64);
        int s1 = __shfl(sv, j+1, 64);
        int s2 = __shfl(sv, j+2, 64);
        int s3 = __shfl(sv, j+3, 64);
        unsigned u0 = msrc[(size_t)s0*64 + lane];
        unsigned u1 = msrc[(size_t)s1*64 + lane];
        unsigned u2 = msrc[(size_t)s2*64 + lane];
        unsigned u3 = msrc[(size_t)s3*64 + lane];
        acc0 += bf_lo(u0) + bf_lo(u1) + bf_lo(u2) + bf_lo(u3);
        acc1 += bf_hi(u0) + bf_hi(u1) + bf_hi(u2) + bf_hi(u3);
      }
      for (; j < kmax; ++j){
        int s = __shfl(sv, j, 64);
        unsigned u = msrc[(size_t)s*64 + lane];
        acc0 += bf_lo(u); acc1 += bf_hi(u);
      }
    }
    if (FIRST){
      #pragma unroll
      for (int off = 32; off > 0; off >>= 1){
        sfx += __shfl_xor(sfx, off, 64);
        sfy += __shfl_xor(sfy, off, 64);
        sfz += __shfl_xor(sfz, off, 64);
        sfw += __shfl_xor(sfw, off, 64);
      }
      if (lane == 0) efsum[n] = make_float4(sfx, sfy, sfz, sfw);
    } else {
      float4 f = efsum[n];
      sfx = f.x; sfy = f.y; sfz = f.z; sfw = f.w;
    }
    acc0 += sfx*We00 + sfy*We10 + sfz*We20 + sfw*We30;
    acc1 += sfx*We01 + sfy*We11 + sfz*We21 + sfw*We31;
    float a0 = fmaxf(acc0, 0.f), a1 = fmaxf(acc1, 0.f);
    h[(size_t)n*64 + lane] = pack_bf16x2(a0, a1);
    float p0 = a0*Wo00 + a1*Wo10;
    float p1 = a0*Wo01 + a1*Wo11;
    #pragma unroll
    for (int off = 32; off > 0; off >>= 1){
      p0 += __shfl_xor(p0, off, 64);
      p1 += __shfl_xor(p1, off, 64);
    }
    if (lane == 0){
      float v0 = Vin[2*n], v1 = Vin[2*n+1];
      Vout[2*n]   = v0 + p0 + bo0;
      Vout[2*n+1] = v1 + p1 + bo1;
    }
  }
}

extern "C" void kernel_launch(void* const* d_in, const int* in_sizes, int n_in,
                              void* d_out, int out_size, void* d_ws, size_t ws_size,
                              hipStream_t stream){
  const float* PQ      = (const float*)d_in[0];
  const int*   senders = (const int*)  d_in[1];
  const int*   recv    = (const int*)  d_in[2];
  const float* ef      = (const float*)d_in[3];
  const float* Win     = (const float*)d_in[4];
  const float* bin     = (const float*)d_in[5];
  const float* Wmsg    = (const float*)d_in[6];
  const float* bmsg    = (const float*)d_in[7];
  const float* Wout    = (const float*)d_in[8];
  const float* bout    = (const float*)d_in[9];
  int N = in_sizes[0] / 2;
  int E = in_sizes[1];
  int L = in_sizes[7] / H;          // 3 layers

  char* base = (char*)d_ws;
  size_t off = 0;
  auto alloc = [&](size_t bytes)->char*{
    char* p = base + off; off += (bytes + 255) & ~(size_t)255; return p;
  };
  unsigned* h      = (unsigned*)alloc((size_t)N*64*4);   // bf16x2-packed
  unsigned* msrc   = (unsigned*)alloc((size_t)N*64*4);
  float*    V      = (float*)   alloc((size_t)N*2*4);
  int*      deg    = (int*)     alloc((size_t)N*4);
  int*      rowptr = (int*)     alloc((size_t)(N+1)*4);
  int*      cursor = (int*)     alloc((size_t)N*4);
  int*      eid    = (int*)     alloc((size_t)E*4);
  int*      ssort  = (int*)     alloc((size_t)E*4);
  float4*   efsum  = (float4*)  alloc((size_t)N*16);
  int*      bsum   = (int*)     alloc((size_t)SCAN_B*4);
  int*      bexcl  = (int*)     alloc((size_t)SCAN_B*4);
  unsigned* Wb     = (unsigned*)alloc((size_t)L*2048*16); // MFMA B fragments, bf16
  if (off > ws_size) return;

  int nb = (N + SCAN_B - 1) / SCAN_B;   // 98 blocks

  hipMemsetAsync(deg, 0, (size_t)N*4, stream);
  init_kernel<<<2048, 256, 0, stream>>>(PQ, Win, bin, h, V, N);
  hist_kernel<<<1024, 256, 0, stream>>>(recv, deg, E);
  scan1_kernel<<<nb, SCAN_B, 0, stream>>>(deg, rowptr, bsum, N);
  scan2_kernel<<<1, SCAN_B, 0, stream>>>(bsum, bexcl, nb);
  scan3_kernel<<<nb, SCAN_B, 0, stream>>>(rowptr, cursor, bexcl, N, E);
  fill_kernel<<<1024, 256, 0, stream>>>(recv, senders, cursor, eid, ssort, E);
  wprep_kernel<<<(L*2048 + 255)/256, 256, 0, stream>>>(Wmsg, Wb, L);

  for (int l = 0; l < L; ++l){
    const float* Wmsg_l = Wmsg + (size_t)l*134*H;
    const float* bmsg_l = bmsg + (size_t)l*H;
    const float* Wout_l = Wout + (size_t)l*H*2;
    const float* bout_l = bout + (size_t)l*2;
    const unsigned* Wb_l = Wb + (size_t)l*2048*4;
    node_msg_mfma<<<1568, 256, 0, stream>>>(V, h, Wmsg_l, bmsg_l, Wb_l, msrc, N);
    float* Vout = (l == L-1) ? (float*)d_out : V;
    if (l == 0)
      agg_update_kernel<true><<<2048, 256, 0, stream>>>(msrc, rowptr, eid, ssort, ef,
                                                        Wmsg_l, Wout_l, bout_l, V, Vout, h, efsum, N);
    else
      agg_update_kernel<false><<<2048, 256, 0, stream>>>(msrc, rowptr, eid, ssort, ef,
                                                         Wmsg_l, Wout_l, bout_l, V, Vout, h, efsum, N);
  }
}